// Round 1
// baseline (5697.131 us; speedup 1.0000x reference)
//
#include <hip/hip_runtime.h>
#include <hip/hip_fp16.h>

// Fused StatePredictor: B=32768, N=20, D=13.
// One thread per (b,n) token; 12 b's (240 tokens) per 256-thread block.
// Per-thread activation row in LDS (fp16, stride 106 -> conflict-free),
// accumulators in registers (all j-loops fully unrolled; k-loops rolled and
// streamed from LDS so no dynamic register indexing).
// Weights read with wave-uniform addresses -> scalar loads + v_fmac v,s,v.
// Per-b reductions (msum / global_state / softmax denom / wsum) via LDS atomics.

#define TB  256
#define GB  12
#define TOK (GB*20)
#define RS  106   // row stride in halves: 53 words, gcd(21,32)=1 -> 2-way (free)

__global__ __launch_bounds__(TB, 2)
void sp_fused(
    const float* __restrict__ state,
    const float* __restrict__ m1w0, const float* __restrict__ m1b0,
    const float* __restrict__ m1w1, const float* __restrict__ m1b1,
    const float* __restrict__ m2w0, const float* __restrict__ m2b0,
    const float* __restrict__ m2w1, const float* __restrict__ m2b1,
    const float* __restrict__ atw0, const float* __restrict__ atb0,
    const float* __restrict__ atw1, const float* __restrict__ atb1,
    const float* __restrict__ atw2, const float* __restrict__ atb2,
    const float* __restrict__ hpw0, const float* __restrict__ hpb0,
    const float* __restrict__ hpw1, const float* __restrict__ hpb1,
    const float* __restrict__ hpw2, const float* __restrict__ hpb2,
    float* __restrict__ out, int Btot)
{
    __shared__ __half rows[TB*RS];      // 54,272 B
    __shared__ float  glob [GB*100];    // 4,800 B  (mask-weighted mean of h1)
    __shared__ float  gcon [GB*100];    // 4,800 B  (glob @ atw0[100:200] + atb0)
    __shared__ float  wsumb[GB*50];     // 2,400 B  (softmax-weighted sum of h2)
    __shared__ float  hcon [GB*100];    // 4,800 B  (wsum @ hpw0[50:100] + hpb0)
    __shared__ float  msum [GB];
    __shared__ float  ssum [GB];
    // total ~71.2 KB -> 2 blocks/CU

    const int  tid = threadIdx.x;
    const int  b0  = blockIdx.x * GB;
    const int  bl  = tid / 20;
    const bool act = (tid < TOK) && (b0 + bl < Btot);
    const int  bls = (tid < TOK) ? bl : 0;

    for (int i = tid; i < GB*100; i += TB) glob[i]  = 0.f;
    for (int i = tid; i < GB*50;  i += TB) wsumb[i] = 0.f;
    if (tid < GB) { msum[tid] = 0.f; ssum[tid] = 0.f; }
    __syncthreads();

    // ---- load token
    float x[13];
    float mask = 0.f;
    #pragma unroll
    for (int k = 0; k < 13; ++k) x[k] = 0.f;
    if (act) {
        const float* sp = state + ((long)b0*20 + tid) * 14;
        #pragma unroll
        for (int k = 0; k < 13; ++k) x[k] = sp[k];
        mask = sp[13];
        atomicAdd(&msum[bl], mask);
    }

    // ---- m1: 13 ->150 (relu) ->100 (relu), hidden streamed, h1 in regs
    float h1[100];
    #pragma unroll
    for (int j = 0; j < 100; ++j) h1[j] = m1b1[j];
    for (int k2 = 0; k2 < 150; ++k2) {
        float t = m1b0[k2];
        #pragma unroll
        for (int k = 0; k < 13; ++k) t = fmaf(x[k], m1w0[k*150 + k2], t);
        t = fmaxf(t, 0.f);
        #pragma unroll
        for (int j = 0; j < 100; ++j) h1[j] = fmaf(t, m1w1[k2*100 + j], h1[j]);
    }
    #pragma unroll
    for (int j = 0; j < 100; ++j) h1[j] = fmaxf(h1[j], 0.f);

    // h1 -> own LDS row (fp16). Rows are thread-private: no barrier needed.
    #pragma unroll
    for (int j = 0; j < 100; ++j) rows[tid*RS + j] = __float2half(h1[j]);

    __syncthreads();                      // msum ready
    float mw = 0.f;
    if (act) { float ms = msum[bl]; if (ms > 0.f) mw = mask / ms; }
    if (mw != 0.f) {
        #pragma unroll 4
        for (int j = 0; j < 100; ++j)
            atomicAdd(&glob[bl*100 + j], mw * h1[j]);
    }
    __syncthreads();                      // glob ready

    // ---- gcon[b][j] = atb0[j] + sum_k glob[b][k] * atw0[100+k][j]  (coop)
    for (int task = tid; task < GB*100; task += TB) {
        int tb = task / 100, j = task - tb*100;
        if (b0 + tb < Btot) {
            float acc = atb0[j];
            for (int k = 0; k < 100; ++k)
                acc = fmaf(glob[tb*100 + k], atw0[(100+k)*100 + j], acc);
            gcon[task] = acc;
        }
    }

    // ---- m2: 100 ->100 (relu) ->50, hidden in 4x25 reg chunks, h2 in regs
    float h2[50];
    #pragma unroll
    for (int j = 0; j < 50; ++j) h2[j] = m2b1[j];
    for (int c = 0; c < 4; ++c) {
        float t2[25];
        #pragma unroll
        for (int u = 0; u < 25; ++u) t2[u] = m2b0[c*25 + u];
        for (int k = 0; k < 100; ++k) {
            float hk = __half2float(rows[tid*RS + k]);
            #pragma unroll
            for (int u = 0; u < 25; ++u) t2[u] = fmaf(hk, m2w0[k*100 + c*25 + u], t2[u]);
        }
        #pragma unroll
        for (int u = 0; u < 25; ++u) {
            float tv = fmaxf(t2[u], 0.f);
            #pragma unroll
            for (int j = 0; j < 50; ++j) h2[j] = fmaf(tv, m2w1[(c*25+u)*50 + j], h2[j]);
        }
    }

    __syncthreads();                      // gcon ready

    // ---- att layer0: ta = relu(h1 @ atw0[:100] + gcon[b])
    float ta[100];
    #pragma unroll
    for (int j = 0; j < 100; ++j) ta[j] = gcon[bls*100 + j];
    for (int k = 0; k < 100; ++k) {
        float hk = __half2float(rows[tid*RS + k]);
        #pragma unroll
        for (int j = 0; j < 100; ++j) ta[j] = fmaf(hk, atw0[k*100 + j], ta[j]);
    }
    #pragma unroll
    for (int j = 0; j < 100; ++j) rows[tid*RS + j] = __float2half(fmaxf(ta[j], 0.f));

    // ---- att layer1
    float ta2[100];
    #pragma unroll
    for (int j = 0; j < 100; ++j) ta2[j] = atb1[j];
    for (int k = 0; k < 100; ++k) {
        float hk = __half2float(rows[tid*RS + k]);
        #pragma unroll
        for (int j = 0; j < 100; ++j) ta2[j] = fmaf(hk, atw1[k*100 + j], ta2[j]);
    }

    // ---- score + masked softmax over n (exactly matches reference semantics)
    float sc = atb2[0];
    #pragma unroll
    for (int k = 0; k < 100; ++k) sc = fmaf(fmaxf(ta2[k], 0.f), atw2[k], sc);
    sc *= mask;
    float se = 0.f;
    if (act && sc != 0.f) se = __expf(sc);
    if (act) atomicAdd(&ssum[bl], se);
    __syncthreads();                      // ssum ready
    float w = 0.f;
    if (act) { float ss = ssum[bl]; if (ss > 0.f) w = se / ss; }
    if (w != 0.f) {
        #pragma unroll 2
        for (int j = 0; j < 50; ++j)
            atomicAdd(&wsumb[bl*50 + j], w * h2[j]);
    }
    __syncthreads();                      // wsumb ready

    // ---- hcon[b][j] = hpb0[j] + sum_k wsumb[b][k] * hpw0[50+k][j]  (coop)
    for (int task = tid; task < GB*100; task += TB) {
        int tb = task / 100, j = task - tb*100;
        if (b0 + tb < Btot) {
            float acc = hpb0[j];
            for (int k = 0; k < 50; ++k)
                acc = fmaf(wsumb[tb*50 + k], hpw0[(50+k)*100 + j], acc);
            hcon[task] = acc;
        }
    }
    __syncthreads();                      // hcon ready

    // ---- hp layer0: th = relu(h2 @ hpw0[:50] + hcon[b])
    #pragma unroll
    for (int j = 0; j < 50; ++j) rows[tid*RS + j] = __float2half(h2[j]);
    float th[100];
    #pragma unroll
    for (int j = 0; j < 100; ++j) th[j] = hcon[bls*100 + j];
    for (int k = 0; k < 50; ++k) {
        float hk = __half2float(rows[tid*RS + k]);
        #pragma unroll
        for (int j = 0; j < 100; ++j) th[j] = fmaf(hk, hpw0[k*100 + j], th[j]);
    }
    #pragma unroll
    for (int j = 0; j < 100; ++j) rows[tid*RS + j] = __float2half(fmaxf(th[j], 0.f));

    // ---- hp layer1
    float th2[100];
    #pragma unroll
    for (int j = 0; j < 100; ++j) th2[j] = hpb1[j];
    for (int k = 0; k < 100; ++k) {
        float hk = __half2float(rows[tid*RS + k]);
        #pragma unroll
        for (int j = 0; j < 100; ++j) th2[j] = fmaf(hk, hpw1[k*100 + j], th2[j]);
    }

    // ---- hp layer2: 100 -> 7 (no relu)
    float o[7];
    #pragma unroll
    for (int j = 0; j < 7; ++j) o[j] = hpb2[j];
    #pragma unroll
    for (int k = 0; k < 100; ++k) {
        float tv = fmaxf(th2[k], 0.f);
        #pragma unroll
        for (int j = 0; j < 7; ++j) o[j] = fmaf(tv, hpw2[k*7 + j], o[j]);
    }
    if (act) {
        float* op = out + ((long)b0*20 + tid) * 7;
        #pragma unroll
        for (int j = 0; j < 7; ++j) op[j] = o[j];
    }
}

extern "C" void kernel_launch(void* const* d_in, const int* in_sizes, int n_in,
                              void* d_out, int out_size, void* d_ws, size_t ws_size,
                              hipStream_t stream) {
    // setup_inputs() dict order: 20 weights/biases then 'state'.
    // Be robust to signature order (state first) by detecting the big buffer.
    int si = 20, wb = 0;
    if (in_sizes[0] > 1000000) { si = 0; wb = 1; }
    const float* state = (const float*)d_in[si];
    const float* W[20];
    for (int i = 0; i < 20; ++i) W[i] = (const float*)d_in[wb + i];
    float* out = (float*)d_out;
    int Btot = in_sizes[si] / (20 * 14);
    dim3 grid((Btot + GB - 1) / GB), block(TB);
    hipLaunchKernelGGL(sp_fused, grid, block, 0, stream,
        state,
        W[0],  W[1],  W[2],  W[3],     // m1
        W[4],  W[5],  W[6],  W[7],     // m2
        W[8],  W[9],  W[10], W[11], W[12], W[13],   // at
        W[14], W[15], W[16], W[17], W[18], W[19],   // hp
        out, Btot);
}

// Round 2
// 3599.394 us; speedup vs baseline: 1.5828x; 1.5828x over previous
//
#include <hip/hip_runtime.h>
#include <hip/hip_fp16.h>

// Fused StatePredictor: B=32768, N=20, D=13.
// One thread per (b,n) token; 12 b's (240 tokens) per 256-thread block.
// Per-thread activation row in LDS (fp16, stride 106 -> conflict-free),
// accumulators in registers (all j-loops FULLY unrolled; k-loops rolled and
// streamed from LDS so no dynamic register indexing ANYWHERE).
// R2 fix: the two reduction atomicAdd loops had partial unrolls (unroll 4 /
// unroll 2) -> runtime j index into h1[]/h2[] -> whole arrays demoted to
// scratch (VGPR=88, 1.3 GB spill writes/dispatch). Full unroll keeps them in
// registers.
// Weights read with wave-uniform addresses -> scalar loads + v_fmac v,s,v.
// Per-b reductions (msum / global_state / softmax denom / wsum) via LDS atomics.

#define TB  256
#define GB  12
#define TOK (GB*20)
#define RS  106   // row stride in halves: 53 words, gcd(53,32)=1 -> 2-way (free)

__global__ __launch_bounds__(TB, 2)
void sp_fused(
    const float* __restrict__ state,
    const float* __restrict__ m1w0, const float* __restrict__ m1b0,
    const float* __restrict__ m1w1, const float* __restrict__ m1b1,
    const float* __restrict__ m2w0, const float* __restrict__ m2b0,
    const float* __restrict__ m2w1, const float* __restrict__ m2b1,
    const float* __restrict__ atw0, const float* __restrict__ atb0,
    const float* __restrict__ atw1, const float* __restrict__ atb1,
    const float* __restrict__ atw2, const float* __restrict__ atb2,
    const float* __restrict__ hpw0, const float* __restrict__ hpb0,
    const float* __restrict__ hpw1, const float* __restrict__ hpb1,
    const float* __restrict__ hpw2, const float* __restrict__ hpb2,
    float* __restrict__ out, int Btot)
{
    __shared__ __half rows[TB*RS];      // 54,272 B
    __shared__ float  glob [GB*100];    // 4,800 B  (mask-weighted mean of h1)
    __shared__ float  gcon [GB*100];    // 4,800 B  (glob @ atw0[100:200] + atb0)
    __shared__ float  wsumb[GB*50];     // 2,400 B  (softmax-weighted sum of h2)
    __shared__ float  hcon [GB*100];    // 4,800 B  (wsum @ hpw0[50:100] + hpb0)
    __shared__ float  msum [GB];
    __shared__ float  ssum [GB];
    // total ~71.2 KB -> 2 blocks/CU (8 waves/CU)

    const int  tid = threadIdx.x;
    const int  b0  = blockIdx.x * GB;
    const int  bl  = tid / 20;
    const bool act = (tid < TOK) && (b0 + bl < Btot);
    const int  bls = (tid < TOK) ? bl : 0;

    for (int i = tid; i < GB*100; i += TB) glob[i]  = 0.f;
    for (int i = tid; i < GB*50;  i += TB) wsumb[i] = 0.f;
    if (tid < GB) { msum[tid] = 0.f; ssum[tid] = 0.f; }
    __syncthreads();

    // ---- load token
    float x[13];
    float mask = 0.f;
    #pragma unroll
    for (int k = 0; k < 13; ++k) x[k] = 0.f;
    if (act) {
        const float* sp = state + ((long)b0*20 + tid) * 14;
        #pragma unroll
        for (int k = 0; k < 13; ++k) x[k] = sp[k];
        mask = sp[13];
        atomicAdd(&msum[bl], mask);
    }

    // ---- m1: 13 ->150 (relu) ->100 (relu), hidden streamed, h1 in regs
    float h1[100];
    #pragma unroll
    for (int j = 0; j < 100; ++j) h1[j] = m1b1[j];
    for (int k2 = 0; k2 < 150; ++k2) {
        float t = m1b0[k2];
        #pragma unroll
        for (int k = 0; k < 13; ++k) t = fmaf(x[k], m1w0[k*150 + k2], t);
        t = fmaxf(t, 0.f);
        #pragma unroll
        for (int j = 0; j < 100; ++j) h1[j] = fmaf(t, m1w1[k2*100 + j], h1[j]);
    }
    #pragma unroll
    for (int j = 0; j < 100; ++j) h1[j] = fmaxf(h1[j], 0.f);

    // h1 -> own LDS row (fp16). Rows are thread-private: no barrier needed.
    #pragma unroll
    for (int j = 0; j < 100; ++j) rows[tid*RS + j] = __float2half(h1[j]);

    __syncthreads();                      // msum ready
    float mw = 0.f;
    if (act) { float ms = msum[bl]; if (ms > 0.f) mw = mask / ms; }
    if (mw != 0.f) {
        #pragma unroll                    // FULL unroll: j must stay static
        for (int j = 0; j < 100; ++j)
            atomicAdd(&glob[bl*100 + j], mw * h1[j]);
    }
    __syncthreads();                      // glob ready

    // ---- gcon[b][j] = atb0[j] + sum_k glob[b][k] * atw0[100+k][j]  (coop)
    for (int task = tid; task < GB*100; task += TB) {
        int tb = task / 100, j = task - tb*100;
        if (b0 + tb < Btot) {
            float acc = atb0[j];
            for (int k = 0; k < 100; ++k)
                acc = fmaf(glob[tb*100 + k], atw0[(100+k)*100 + j], acc);
            gcon[task] = acc;
        }
    }

    // ---- m2: 100 ->100 (relu) ->50, hidden in 4x25 reg chunks, h2 in regs
    float h2[50];
    #pragma unroll
    for (int j = 0; j < 50; ++j) h2[j] = m2b1[j];
    for (int c = 0; c < 4; ++c) {
        float t2[25];
        #pragma unroll
        for (int u = 0; u < 25; ++u) t2[u] = m2b0[c*25 + u];
        for (int k = 0; k < 100; ++k) {
            float hk = __half2float(rows[tid*RS + k]);
            #pragma unroll
            for (int u = 0; u < 25; ++u) t2[u] = fmaf(hk, m2w0[k*100 + c*25 + u], t2[u]);
        }
        #pragma unroll
        for (int u = 0; u < 25; ++u) {
            float tv = fmaxf(t2[u], 0.f);
            #pragma unroll
            for (int j = 0; j < 50; ++j) h2[j] = fmaf(tv, m2w1[(c*25+u)*50 + j], h2[j]);
        }
    }

    __syncthreads();                      // gcon ready

    // ---- att layer0: ta = relu(h1 @ atw0[:100] + gcon[b])
    float ta[100];
    #pragma unroll
    for (int j = 0; j < 100; ++j) ta[j] = gcon[bls*100 + j];
    for (int k = 0; k < 100; ++k) {
        float hk = __half2float(rows[tid*RS + k]);
        #pragma unroll
        for (int j = 0; j < 100; ++j) ta[j] = fmaf(hk, atw0[k*100 + j], ta[j]);
    }
    #pragma unroll
    for (int j = 0; j < 100; ++j) rows[tid*RS + j] = __float2half(fmaxf(ta[j], 0.f));

    // ---- att layer1
    float ta2[100];
    #pragma unroll
    for (int j = 0; j < 100; ++j) ta2[j] = atb1[j];
    for (int k = 0; k < 100; ++k) {
        float hk = __half2float(rows[tid*RS + k]);
        #pragma unroll
        for (int j = 0; j < 100; ++j) ta2[j] = fmaf(hk, atw1[k*100 + j], ta2[j]);
    }

    // ---- score + masked softmax over n (exactly matches reference semantics)
    float sc = atb2[0];
    #pragma unroll
    for (int k = 0; k < 100; ++k) sc = fmaf(fmaxf(ta2[k], 0.f), atw2[k], sc);
    sc *= mask;
    float se = 0.f;
    if (act && sc != 0.f) se = __expf(sc);
    if (act) atomicAdd(&ssum[bl], se);
    __syncthreads();                      // ssum ready
    float w = 0.f;
    if (act) { float ss = ssum[bl]; if (ss > 0.f) w = se / ss; }
    if (w != 0.f) {
        #pragma unroll                    // FULL unroll: j must stay static
        for (int j = 0; j < 50; ++j)
            atomicAdd(&wsumb[bl*50 + j], w * h2[j]);
    }
    __syncthreads();                      // wsumb ready

    // ---- hcon[b][j] = hpb0[j] + sum_k wsumb[b][k] * hpw0[50+k][j]  (coop)
    for (int task = tid; task < GB*100; task += TB) {
        int tb = task / 100, j = task - tb*100;
        if (b0 + tb < Btot) {
            float acc = hpb0[j];
            for (int k = 0; k < 50; ++k)
                acc = fmaf(wsumb[tb*50 + k], hpw0[(50+k)*100 + j], acc);
            hcon[task] = acc;
        }
    }
    __syncthreads();                      // hcon ready

    // ---- hp layer0: th = relu(h2 @ hpw0[:50] + hcon[b])
    #pragma unroll
    for (int j = 0; j < 50; ++j) rows[tid*RS + j] = __float2half(h2[j]);
    float th[100];
    #pragma unroll
    for (int j = 0; j < 100; ++j) th[j] = hcon[bls*100 + j];
    for (int k = 0; k < 50; ++k) {
        float hk = __half2float(rows[tid*RS + k]);
        #pragma unroll
        for (int j = 0; j < 100; ++j) th[j] = fmaf(hk, hpw0[k*100 + j], th[j]);
    }
    #pragma unroll
    for (int j = 0; j < 100; ++j) rows[tid*RS + j] = __float2half(fmaxf(th[j], 0.f));

    // ---- hp layer1
    float th2[100];
    #pragma unroll
    for (int j = 0; j < 100; ++j) th2[j] = hpb1[j];
    for (int k = 0; k < 100; ++k) {
        float hk = __half2float(rows[tid*RS + k]);
        #pragma unroll
        for (int j = 0; j < 100; ++j) th2[j] = fmaf(hk, hpw1[k*100 + j], th2[j]);
    }

    // ---- hp layer2: 100 -> 7 (no relu)
    float o[7];
    #pragma unroll
    for (int j = 0; j < 7; ++j) o[j] = hpb2[j];
    #pragma unroll
    for (int k = 0; k < 100; ++k) {
        float tv = fmaxf(th2[k], 0.f);
        #pragma unroll
        for (int j = 0; j < 7; ++j) o[j] = fmaf(tv, hpw2[k*7 + j], o[j]);
    }
    if (act) {
        float* op = out + ((long)b0*20 + tid) * 7;
        #pragma unroll
        for (int j = 0; j < 7; ++j) op[j] = o[j];
    }
}

extern "C" void kernel_launch(void* const* d_in, const int* in_sizes, int n_in,
                              void* d_out, int out_size, void* d_ws, size_t ws_size,
                              hipStream_t stream) {
    // setup_inputs() dict order: 20 weights/biases then 'state'.
    // Be robust to signature order (state first) by detecting the big buffer.
    int si = 20, wb = 0;
    if (in_sizes[0] > 1000000) { si = 0; wb = 1; }
    const float* state = (const float*)d_in[si];
    const float* W[20];
    for (int i = 0; i < 20; ++i) W[i] = (const float*)d_in[wb + i];
    float* out = (float*)d_out;
    int Btot = in_sizes[si] / (20 * 14);
    dim3 grid((Btot + GB - 1) / GB), block(TB);
    hipLaunchKernelGGL(sp_fused, grid, block, 0, stream,
        state,
        W[0],  W[1],  W[2],  W[3],     // m1
        W[4],  W[5],  W[6],  W[7],     // m2
        W[8],  W[9],  W[10], W[11], W[12], W[13],   // at
        W[14], W[15], W[16], W[17], W[18], W[19],   // hp
        out, Btot);
}

// Round 4
// 833.859 us; speedup vs baseline: 6.8322x; 4.3166x over previous
//
#include <hip/hip_runtime.h>

// R4: bf16 MFMA rewrite (fresh transcription). One block = 8 batch elems =
// 160 tokens (M), 512 thr = 8 waves. v_mfma_f32_16x16x32_bf16 for ALL
// matmuls via ONE gemm template: A = weight tiles wT[n][k] (bf16 LDS, fully
// zero-padded to KT*32), B = act rows act[m][k] (bf16 LDS), D[row=n=quad*4+
// reg][col=m=lane&15] -> b64 store of 4 consecutive n. fp32 accum, bias in
// acc-init. x staged into bufA so even layer0 uses the template.
// Rationale: every layout verification in the docs is bf16 (m89/m91/m118-122);
// R3's f16 variant produced structural errors. Reductions/glue on VALU.

typedef short sx8 __attribute__((ext_vector_type(8)));
typedef short sx4 __attribute__((ext_vector_type(4)));
typedef float fx4 __attribute__((ext_vector_type(4)));

#define TB   512
#define NW   8
#define MTOK 160

// LDS byte offsets (16B aligned)
#define OFF_WBUF 0        // weight stage, max 112*136*2 = 30464
#define OFF_BUFT 30464    // 160 x stride168 = 53760
#define OFF_BUFA 84224    // 160 x stride136 = 43520
#define OFF_BUFH 127744   // 160 x stride72  = 23040
#define OFF_BIAS 150784   // 848 f32
#define OFF_GRC  154176   // 816 f32
#define OFF_WRC  157440   // 816 f32
#define OFF_SC   160704   // 160 f32
#define OFF_MASK 161344   // 160 f32
#define OFF_MSUM 161984   // 8 f32
#define OFF_SSUM 162016   // 8 f32
#define SMEM_BYTES 162048

#define B_M1B0 0
#define B_M1B1 152
#define B_M2B0 256
#define B_M2B1 360
#define B_ATB0 416
#define B_ATB1 520
#define B_HPB0 624
#define B_HPB1 728
#define B_HPB2 832

__device__ __forceinline__ short f2b(float f) {
    unsigned u = __builtin_bit_cast(unsigned, f);
    u += 0x7FFFu + ((u >> 16) & 1u);          // RNE
    return (short)(u >> 16);
}
__device__ __forceinline__ float b2f(short h) {
    unsigned u = ((unsigned)(unsigned short)h) << 16;
    return __builtin_bit_cast(float, u);
}

// stage W[K][N] (global f32 row-major) -> wT[nl][k] bf16 for nl in [0,NR),
// ng = nbase+nl; zero outside (k<KR, ng<Nsrc); k staged through KPAD (mult 8).
__device__ __forceinline__ void stageW(const float* __restrict__ W, int N,
                                       int KR, int KPAD, int nbase, int NR,
                                       int Nsrc, short* wT, int wst, int tid) {
    int K8 = KPAD >> 3;
    for (int idx = tid; idx < NR * K8; idx += TB) {
        int k8 = idx / NR, nl = idx - k8 * NR;
        int ng = nbase + nl, k0 = k8 << 3;
        sx8 h;
        #pragma unroll
        for (int i = 0; i < 8; ++i) {
            int k = k0 + i;
            float v = (k < KR && ng < Nsrc) ? W[k * N + ng] : 0.f;
            h[i] = f2b(v);
        }
        *(sx8*)(wT + nl * wst + k0) = h;
    }
}

// zero act cols [112,128)
__device__ __forceinline__ void zpad(short* buf, int stride, int tid) {
    for (int i = tid; i < MTOK * 2; i += TB) {
        int row = i >> 1, c = 112 + ((i & 1) << 3);
        sx8 z = {0, 0, 0, 0, 0, 0, 0, 0};
        *(sx8*)(buf + row * stride + c) = z;
    }
}

// out[m][nbase+n] = (relu)(init + sum_k act[m][k] * W[k][nbase+n])
template <int KT, bool RELU>
__device__ __forceinline__ void gemm(const short* wT, int wst,
                                     const short* aIn, int ist,
                                     short* aOut, int ost,
                                     const float* initp, int initBstride,
                                     int Mt, int Nt, int nbase, int Nreal,
                                     int wave, int lm, int lq) {
    for (int tix = wave; tix < Mt * Nt; tix += NW) {
        int mt = tix / Nt, nt = tix - mt * Nt;
        int tok = mt * 16 + lm;
        int n0l = nt * 16 + lq * 4;
        const float* ip = initBstride
                              ? (initp + (tok / 20) * initBstride + nbase + n0l)
                              : (initp + nbase + n0l);
        fx4 acc = *(const fx4*)ip;
        fx4 acc2 = {0.f, 0.f, 0.f, 0.f};
        const short* ap = wT + (nt * 16 + lm) * wst + lq * 8;
        const short* bp = aIn + tok * ist + lq * 8;
        #pragma unroll
        for (int kt = 0; kt < KT; ++kt) {
            sx8 a = *(const sx8*)(ap + kt * 32);
            sx8 b = *(const sx8*)(bp + kt * 32);
            if (kt & 1)
                acc2 = __builtin_amdgcn_mfma_f32_16x16x32_bf16(a, b, acc2, 0, 0, 0);
            else
                acc = __builtin_amdgcn_mfma_f32_16x16x32_bf16(a, b, acc, 0, 0, 0);
        }
        if (KT > 1) {
            acc[0] += acc2[0]; acc[1] += acc2[1];
            acc[2] += acc2[2]; acc[3] += acc2[3];
        }
        sx4 hv;
        #pragma unroll
        for (int r = 0; r < 4; ++r) {
            float v = acc[r];
            if (RELU) v = fmaxf(v, 0.f);
            if (nbase + n0l + r >= Nreal) v = 0.f;
            hv[r] = f2b(v);
        }
        *(sx4*)(aOut + tok * ost + nbase + n0l) = hv;
    }
}

__global__ __launch_bounds__(TB, 1) void sp_mfma_bf16(
    const float* __restrict__ state,
    const float* __restrict__ m1w0, const float* __restrict__ m1b0,
    const float* __restrict__ m1w1, const float* __restrict__ m1b1,
    const float* __restrict__ m2w0, const float* __restrict__ m2b0,
    const float* __restrict__ m2w1, const float* __restrict__ m2b1,
    const float* __restrict__ atw0, const float* __restrict__ atb0,
    const float* __restrict__ atw1, const float* __restrict__ atb1,
    const float* __restrict__ atw2, const float* __restrict__ atb2,
    const float* __restrict__ hpw0, const float* __restrict__ hpb0,
    const float* __restrict__ hpw1, const float* __restrict__ hpb1,
    const float* __restrict__ hpw2, const float* __restrict__ hpb2,
    float* __restrict__ out)
{
    __shared__ __align__(16) unsigned char smem[SMEM_BYTES];
    short* wbuf  = (short*)(smem + OFF_WBUF);
    short* bufT  = (short*)(smem + OFF_BUFT);
    short* bufA  = (short*)(smem + OFF_BUFA);
    short* bufH2 = (short*)(smem + OFF_BUFH);
    float* biasv = (float*)(smem + OFF_BIAS);
    float* grc   = (float*)(smem + OFF_GRC);
    float* wrc   = (float*)(smem + OFF_WRC);
    float* scv   = (float*)(smem + OFF_SC);
    float* maskv = (float*)(smem + OFF_MASK);
    float* msum  = (float*)(smem + OFF_MSUM);
    float* ssum  = (float*)(smem + OFF_SSUM);

    const int tid  = threadIdx.x;
    const int lane = tid & 63;
    const int wave = tid >> 6;
    const int lm   = lane & 15;
    const int lq   = lane >> 4;
    const long gt0 = (long)blockIdx.x * MTOK;

    // ---- phase 1: biases, mask, x -> bufA rows [0,32), m1w0 stage
    {
        const float* bs[9] = {m1b0, m1b1, m2b0, m2b1, atb0, atb1, hpb0, hpb1, hpb2};
        const int off[9] = {B_M1B0, B_M1B1, B_M2B0, B_M2B1, B_ATB0, B_ATB1, B_HPB0, B_HPB1, B_HPB2};
        const int sz[9]  = {150, 100, 100, 50, 100, 100, 100, 100, 7};
        const int pd[9]  = {152, 104, 104, 56, 104, 104, 104, 104, 16};
        #pragma unroll
        for (int r = 0; r < 9; ++r)
            for (int i = tid; i < pd[r]; i += TB)
                biasv[off[r] + i] = (i < sz[r]) ? bs[r][i] : 0.f;
        if (tid < MTOK) maskv[tid] = state[(gt0 + tid) * 14 + 13];
        for (int idx = tid; idx < MTOK * 4; idx += TB) {
            int row = idx >> 2, seg = idx & 3;
            const float* xp = state + (gt0 + row) * 14;
            sx8 h;
            #pragma unroll
            for (int i = 0; i < 8; ++i) {
                int k = seg * 8 + i;
                float v = (k < 13) ? xp[k] : 0.f;
                h[i] = f2b(v);
            }
            *(sx8*)(bufA + row * 136 + seg * 8) = h;
        }
        stageW(m1w0, 150, 13, 32, 0, 160, 150, wbuf, 40, tid);
    }
    __syncthreads();

    // ---- msum + m1L0 (13->150, relu): x(bufA) -> bufT
    if (tid < 8) {
        float s = 0.f;
        #pragma unroll
        for (int n = 0; n < 20; ++n) s += maskv[tid * 20 + n];
        msum[tid] = s;
    }
    gemm<1, true>(wbuf, 40, bufA, 136, bufT, 168, biasv + B_M1B0, 0,
                  10, 10, 0, 150, wave, lm, lq);
    __syncthreads();

    // ---- m1L1 (150->100, relu): bufT -> bufA (h1), N-split staging
    stageW(m1w1, 100, 150, 160, 0, 64, 100, wbuf, 168, tid);
    __syncthreads();
    gemm<5, true>(wbuf, 168, bufT, 168, bufA, 136, biasv + B_M1B1, 0,
                  10, 4, 0, 100, wave, lm, lq);
    __syncthreads();
    stageW(m1w1, 100, 150, 160, 64, 48, 100, wbuf, 168, tid);
    __syncthreads();
    gemm<5, true>(wbuf, 168, bufT, 168, bufA, 136, biasv + B_M1B1, 0,
                  10, 3, 64, 100, wave, lm, lq);
    zpad(bufA, 136, tid);
    __syncthreads();

    // ---- glob[b][j] = (sum_n mask*h1)/msum -> grc
    for (int task = tid; task < 800; task += TB) {
        int b = task / 100, j = task - b * 100;
        float ms = msum[b];
        float inv = (ms > 0.f) ? 1.f / ms : 0.f;
        float a = 0.f;
        #pragma unroll
        for (int n = 0; n < 20; ++n)
            a = fmaf(maskv[b * 20 + n], b2f(bufA[(b * 20 + n) * 136 + j]), a);
        grc[task] = a * inv;
    }
    __syncthreads();

    // ---- gcon = atb0 + glob @ atw0[100:200] (register-staged overwrite)
    {
        float g0 = 0.f, g1 = 0.f;
        {
            int b = tid / 100, j = tid - b * 100;
            float a = biasv[B_ATB0 + j];
            #pragma unroll 10
            for (int k = 0; k < 100; ++k)
                a = fmaf(grc[b * 100 + k], atw0[(100 + k) * 100 + j], a);
            g0 = a;
        }
        int t1 = tid + TB;
        if (t1 < 800) {
            int b = t1 / 100, j = t1 - b * 100;
            float a = biasv[B_ATB0 + j];
            #pragma unroll 10
            for (int k = 0; k < 100; ++k)
                a = fmaf(grc[b * 100 + k], atw0[(100 + k) * 100 + j], a);
            g1 = a;
        }
        __syncthreads();
        grc[tid] = g0;
        if (t1 < 800) grc[t1] = g1;
        stageW(m2w0, 100, 100, 128, 0, 112, 100, wbuf, 136, tid);
    }
    __syncthreads();

    // ---- m2L0 (100->100, relu): h1(bufA) -> bufT (t2)
    gemm<4, true>(wbuf, 136, bufA, 136, bufT, 168, biasv + B_M2B0, 0,
                  10, 7, 0, 100, wave, lm, lq);
    zpad(bufT, 168, tid);
    __syncthreads();
    stageW(m2w1, 50, 100, 128, 0, 64, 50, wbuf, 136, tid);
    __syncthreads();
    // ---- m2L1 (100->50, no relu): bufT -> bufH2 (h2)
    gemm<4, false>(wbuf, 136, bufT, 168, bufH2, 72, biasv + B_M2B1, 0,
                   10, 4, 0, 50, wave, lm, lq);
    __syncthreads();
    stageW(atw0, 100, 100, 128, 0, 112, 100, wbuf, 136, tid);
    __syncthreads();

    // ---- atL0 (100->100, relu, init=gcon): h1(bufA) -> bufT (ta)
    gemm<4, true>(wbuf, 136, bufA, 136, bufT, 168, grc, 100,
                  10, 7, 0, 100, wave, lm, lq);
    zpad(bufT, 168, tid);
    __syncthreads();
    stageW(atw1, 100, 100, 128, 0, 112, 100, wbuf, 136, tid);
    __syncthreads();
    // ---- atL1 (100->100, relu): bufT -> bufA (ta2)
    gemm<4, true>(wbuf, 136, bufT, 168, bufA, 136, biasv + B_ATB1, 0,
                  10, 7, 0, 100, wave, lm, lq);
    __syncthreads();

    // ---- scores + masked exp (matches reference semantics)
    if (tid < MTOK) {
        float s = atb2[0];
        const short* tp = bufA + tid * 136;
        #pragma unroll
        for (int k8 = 0; k8 < 13; ++k8) {
            sx8 v = *(const sx8*)(tp + k8 * 8);
            #pragma unroll
            for (int i = 0; i < 8; ++i) {
                int k = k8 * 8 + i;
                if (k < 100) s = fmaf(b2f(v[i]), atw2[k], s);
            }
        }
        s *= maskv[tid];
        scv[tid] = (s != 0.f) ? __expf(s) : 0.f;
    }
    __syncthreads();
    if (tid < 8) {
        float s = 0.f;
        #pragma unroll
        for (int n = 0; n < 20; ++n) s += scv[tid * 20 + n];
        ssum[tid] = s;
    }
    __syncthreads();
    if (tid < MTOK) {
        float ss = ssum[tid / 20];
        scv[tid] = (ss > 0.f) ? scv[tid] / ss : 0.f;
    }
    __syncthreads();

    // ---- wsum[b][j] = sum_n w*h2 -> wrc[0,400)
    if (tid < 400) {
        int b = tid / 50, j = tid - b * 50;
        float a = 0.f;
        #pragma unroll
        for (int n = 0; n < 20; ++n)
            a = fmaf(scv[b * 20 + n], b2f(bufH2[(b * 20 + n) * 72 + j]), a);
        wrc[b * 50 + j] = a;
    }
    __syncthreads();

    // ---- hcon = hpb0 + wsum @ hpw0[50:100] (register-staged overwrite)
    {
        float g0 = 0.f, g1 = 0.f;
        {
            int b = tid / 100, j = tid - b * 100;
            float a = biasv[B_HPB0 + j];
            #pragma unroll 10
            for (int k = 0; k < 50; ++k)
                a = fmaf(wrc[b * 50 + k], hpw0[(50 + k) * 100 + j], a);
            g0 = a;
        }
        int t1 = tid + TB;
        if (t1 < 800) {
            int b = t1 / 100, j = t1 - b * 100;
            float a = biasv[B_HPB0 + j];
            #pragma unroll 10
            for (int k = 0; k < 50; ++k)
                a = fmaf(wrc[b * 50 + k], hpw0[(50 + k) * 100 + j], a);
            g1 = a;
        }
        __syncthreads();
        wrc[tid] = g0;
        if (t1 < 800) wrc[t1] = g1;
        stageW(hpw0, 100, 50, 64, 0, 112, 100, wbuf, 72, tid);
    }
    __syncthreads();

    // ---- hpL0 (50->100, relu, init=hcon): h2(bufH2) -> bufT (th)
    gemm<2, true>(wbuf, 72, bufH2, 72, bufT, 168, wrc, 100,
                  10, 7, 0, 100, wave, lm, lq);
    zpad(bufT, 168, tid);
    __syncthreads();
    stageW(hpw1, 100, 100, 128, 0, 112, 100, wbuf, 136, tid);
    __syncthreads();
    // ---- hpL1 (100->100, relu): bufT -> bufA (th2)
    gemm<4, true>(wbuf, 136, bufT, 168, bufA, 136, biasv + B_HPB1, 0,
                  10, 7, 0, 100, wave, lm, lq);
    zpad(bufA, 136, tid);
    __syncthreads();
    stageW(hpw2, 7, 100, 128, 0, 16, 7, wbuf, 136, tid);
    __syncthreads();

    // ---- hpL2 (100->7) -> global out
    for (int mt = wave; mt < 10; mt += NW) {
        int tok = mt * 16 + lm;
        fx4 acc = *(const fx4*)(biasv + B_HPB2 + lq * 4);
        fx4 acc2 = {0.f, 0.f, 0.f, 0.f};
        const short* ap = wbuf + lm * 136 + lq * 8;
        const short* bp = bufA + tok * 136 + lq * 8;
        #pragma unroll
        for (int kt = 0; kt < 4; ++kt) {
            sx8 a = *(const sx8*)(ap + kt * 32);
            sx8 b = *(const sx8*)(bp + kt * 32);
            if (kt & 1)
                acc2 = __builtin_amdgcn_mfma_f32_16x16x32_bf16(a, b, acc2, 0, 0, 0);
            else
                acc = __builtin_amdgcn_mfma_f32_16x16x32_bf16(a, b, acc, 0, 0, 0);
        }
        acc[0] += acc2[0]; acc[1] += acc2[1]; acc[2] += acc2[2]; acc[3] += acc2[3];
        #pragma unroll
        for (int r = 0; r < 4; ++r) {
            int n = lq * 4 + r;
            if (n < 7) out[(gt0 + tok) * 7 + n] = acc[r];
        }
    }
}

extern "C" void kernel_launch(void* const* d_in, const int* in_sizes, int n_in,
                              void* d_out, int out_size, void* d_ws, size_t ws_size,
                              hipStream_t stream) {
    int si = 20, wb = 0;
    if (in_sizes[0] > 1000000) { si = 0; wb = 1; }
    const float* state = (const float*)d_in[si];
    const float* W[20];
    for (int i = 0; i < 20; ++i) W[i] = (const float*)d_in[wb + i];
    float* out = (float*)d_out;
    int Btot = in_sizes[si] / (20 * 14);
    int nblocks = Btot / 8;   // 8 b's (160 tokens) per block
    hipLaunchKernelGGL(sp_mfma_bf16, dim3(nblocks), dim3(TB), 0, stream,
        state,
        W[0], W[1], W[2], W[3],
        W[4], W[5], W[6], W[7],
        W[8], W[9], W[10], W[11], W[12], W[13],
        W[14], W[15], W[16], W[17], W[18], W[19],
        out);
}

// Round 5
// 629.035 us; speedup vs baseline: 9.0569x; 1.3256x over previous
//
#include <hip/hip_runtime.h>

// R5: same verified bf16-MFMA dataflow as R4, two scheduling changes:
//  (1) TB 512 -> 1024 (16 waves): occupancy 8 -> 16 waves/CU; halves staging
//      and glue time; 4 waves/SIMD to hide MFMA/LDS latency. LDS unchanged.
//  (2) A-fragment hoist: work item = (n-tile, m-chunk); weight frags loaded
//      once into regs, reused over m-chunk rows -> ~45% less gemm LDS read.
// Dataflow, LDS layout, and numerics are bit-identical to R4 (passed,
// absmax 6.8e-3).

typedef short sx8 __attribute__((ext_vector_type(8)));
typedef short sx4 __attribute__((ext_vector_type(4)));
typedef float fx4 __attribute__((ext_vector_type(4)));

#define TB   1024
#define NW   16
#define MTOK 160

// LDS byte offsets (16B aligned)
#define OFF_WBUF 0        // weight stage, max 112*136*2 = 30464
#define OFF_BUFT 30464    // 160 x stride168 = 53760
#define OFF_BUFA 84224    // 160 x stride136 = 43520
#define OFF_BUFH 127744   // 160 x stride72  = 23040
#define OFF_BIAS 150784   // 848 f32
#define OFF_GRC  154176   // 816 f32
#define OFF_WRC  157440   // 816 f32
#define OFF_SC   160704   // 160 f32
#define OFF_MASK 161344   // 160 f32
#define OFF_MSUM 161984   // 8 f32
#define OFF_SSUM 162016   // 8 f32
#define SMEM_BYTES 162048

#define B_M1B0 0
#define B_M1B1 152
#define B_M2B0 256
#define B_M2B1 360
#define B_ATB0 416
#define B_ATB1 520
#define B_HPB0 624
#define B_HPB1 728
#define B_HPB2 832

__device__ __forceinline__ short f2b(float f) {
    unsigned u = __builtin_bit_cast(unsigned, f);
    u += 0x7FFFu + ((u >> 16) & 1u);          // RNE
    return (short)(u >> 16);
}
__device__ __forceinline__ float b2f(short h) {
    unsigned u = ((unsigned)(unsigned short)h) << 16;
    return __builtin_bit_cast(float, u);
}

// stage W[K][N] (global f32 row-major) -> wT[nl][k] bf16 for nl in [0,NR),
// ng = nbase+nl; zero outside (k<KR, ng<Nsrc); k staged through KPAD (mult 8).
__device__ __forceinline__ void stageW(const float* __restrict__ W, int N,
                                       int KR, int KPAD, int nbase, int NR,
                                       int Nsrc, short* wT, int wst, int tid) {
    int K8 = KPAD >> 3;
    for (int idx = tid; idx < NR * K8; idx += TB) {
        int k8 = idx / NR, nl = idx - k8 * NR;
        int ng = nbase + nl, k0 = k8 << 3;
        sx8 h;
        #pragma unroll
        for (int i = 0; i < 8; ++i) {
            int k = k0 + i;
            float v = (k < KR && ng < Nsrc) ? W[k * N + ng] : 0.f;
            h[i] = f2b(v);
        }
        *(sx8*)(wT + nl * wst + k0) = h;
    }
}

// zero act cols [112,128)
__device__ __forceinline__ void zpad(short* buf, int stride, int tid) {
    for (int i = tid; i < MTOK * 2; i += TB) {
        int row = i >> 1, c = 112 + ((i & 1) << 3);
        sx8 z = {0, 0, 0, 0, 0, 0, 0, 0};
        *(sx8*)(buf + row * stride + c) = z;
    }
}

// out[m][nbase+n] = (relu)(init + sum_k act[m][k] * W[k][nbase+n])
// Work item = (n-tile, m-chunk of 10/MS m-tiles); A frags hoisted per item.
template <int KT, int MS, bool RELU>
__device__ __forceinline__ void gemm(const short* wT, int wst,
                                     const short* aIn, int ist,
                                     short* aOut, int ost,
                                     const float* initp, int initBstride,
                                     int Nt, int nbase, int Nreal,
                                     int wave, int lm, int lq) {
    constexpr int MC = 10 / MS;
    for (int tix = wave; tix < Nt * MS; tix += NW) {
        int nt = tix / MS, mh = tix - nt * MS;
        int n0l = nt * 16 + lq * 4;
        const short* ap = wT + (nt * 16 + lm) * wst + lq * 8;
        sx8 afr[KT];
        #pragma unroll
        for (int kt = 0; kt < KT; ++kt) afr[kt] = *(const sx8*)(ap + kt * 32);
        #pragma unroll
        for (int mi = 0; mi < MC; ++mi) {
            int mt = mh * MC + mi;
            int tok = mt * 16 + lm;
            const float* ip = initBstride
                                  ? (initp + (tok / 20) * initBstride + nbase + n0l)
                                  : (initp + nbase + n0l);
            fx4 acc = *(const fx4*)ip;
            fx4 acc2 = {0.f, 0.f, 0.f, 0.f};
            const short* bp = aIn + tok * ist + lq * 8;
            #pragma unroll
            for (int kt = 0; kt < KT; ++kt) {
                sx8 b = *(const sx8*)(bp + kt * 32);
                if (kt & 1)
                    acc2 = __builtin_amdgcn_mfma_f32_16x16x32_bf16(afr[kt], b, acc2, 0, 0, 0);
                else
                    acc = __builtin_amdgcn_mfma_f32_16x16x32_bf16(afr[kt], b, acc, 0, 0, 0);
            }
            if (KT > 1) {
                acc[0] += acc2[0]; acc[1] += acc2[1];
                acc[2] += acc2[2]; acc[3] += acc2[3];
            }
            sx4 hv;
            #pragma unroll
            for (int r = 0; r < 4; ++r) {
                float v = acc[r];
                if (RELU) v = fmaxf(v, 0.f);
                if (nbase + n0l + r >= Nreal) v = 0.f;
                hv[r] = f2b(v);
            }
            *(sx4*)(aOut + tok * ost + nbase + n0l) = hv;
        }
    }
}

__global__ __launch_bounds__(TB, 1) void sp_mfma_bf16(
    const float* __restrict__ state,
    const float* __restrict__ m1w0, const float* __restrict__ m1b0,
    const float* __restrict__ m1w1, const float* __restrict__ m1b1,
    const float* __restrict__ m2w0, const float* __restrict__ m2b0,
    const float* __restrict__ m2w1, const float* __restrict__ m2b1,
    const float* __restrict__ atw0, const float* __restrict__ atb0,
    const float* __restrict__ atw1, const float* __restrict__ atb1,
    const float* __restrict__ atw2, const float* __restrict__ atb2,
    const float* __restrict__ hpw0, const float* __restrict__ hpb0,
    const float* __restrict__ hpw1, const float* __restrict__ hpb1,
    const float* __restrict__ hpw2, const float* __restrict__ hpb2,
    float* __restrict__ out)
{
    __shared__ __align__(16) unsigned char smem[SMEM_BYTES];
    short* wbuf  = (short*)(smem + OFF_WBUF);
    short* bufT  = (short*)(smem + OFF_BUFT);
    short* bufA  = (short*)(smem + OFF_BUFA);
    short* bufH2 = (short*)(smem + OFF_BUFH);
    float* biasv = (float*)(smem + OFF_BIAS);
    float* grc   = (float*)(smem + OFF_GRC);
    float* wrc   = (float*)(smem + OFF_WRC);
    float* scv   = (float*)(smem + OFF_SC);
    float* maskv = (float*)(smem + OFF_MASK);
    float* msum  = (float*)(smem + OFF_MSUM);
    float* ssum  = (float*)(smem + OFF_SSUM);

    const int tid  = threadIdx.x;
    const int lane = tid & 63;
    const int wave = tid >> 6;
    const int lm   = lane & 15;
    const int lq   = lane >> 4;
    const long gt0 = (long)blockIdx.x * MTOK;

    // ---- phase 1: biases, mask, x -> bufA rows, m1w0 stage
    {
        const float* bs[9] = {m1b0, m1b1, m2b0, m2b1, atb0, atb1, hpb0, hpb1, hpb2};
        const int off[9] = {B_M1B0, B_M1B1, B_M2B0, B_M2B1, B_ATB0, B_ATB1, B_HPB0, B_HPB1, B_HPB2};
        const int sz[9]  = {150, 100, 100, 50, 100, 100, 100, 100, 7};
        const int pd[9]  = {152, 104, 104, 56, 104, 104, 104, 104, 16};
        #pragma unroll
        for (int r = 0; r < 9; ++r)
            for (int i = tid; i < pd[r]; i += TB)
                biasv[off[r] + i] = (i < sz[r]) ? bs[r][i] : 0.f;
        if (tid < MTOK) maskv[tid] = state[(gt0 + tid) * 14 + 13];
        for (int idx = tid; idx < MTOK * 4; idx += TB) {
            int row = idx >> 2, seg = idx & 3;
            const float* xp = state + (gt0 + row) * 14;
            sx8 h;
            #pragma unroll
            for (int i = 0; i < 8; ++i) {
                int k = seg * 8 + i;
                float v = (k < 13) ? xp[k] : 0.f;
                h[i] = f2b(v);
            }
            *(sx8*)(bufA + row * 136 + seg * 8) = h;
        }
        stageW(m1w0, 150, 13, 32, 0, 160, 150, wbuf, 40, tid);
    }
    __syncthreads();

    // ---- msum + m1L0 (13->150, relu): x(bufA) -> bufT
    if (tid < 8) {
        float s = 0.f;
        #pragma unroll
        for (int n = 0; n < 20; ++n) s += maskv[tid * 20 + n];
        msum[tid] = s;
    }
    gemm<1, 2, true>(wbuf, 40, bufA, 136, bufT, 168, biasv + B_M1B0, 0,
                     10, 0, 150, wave, lm, lq);
    __syncthreads();

    // ---- m1L1 (150->100, relu): bufT -> bufA (h1), N-split staging
    stageW(m1w1, 100, 150, 160, 0, 64, 100, wbuf, 168, tid);
    __syncthreads();
    gemm<5, 5, true>(wbuf, 168, bufT, 168, bufA, 136, biasv + B_M1B1, 0,
                     4, 0, 100, wave, lm, lq);
    __syncthreads();
    stageW(m1w1, 100, 150, 160, 64, 48, 100, wbuf, 168, tid);
    __syncthreads();
    gemm<5, 5, true>(wbuf, 168, bufT, 168, bufA, 136, biasv + B_M1B1, 0,
                     3, 64, 100, wave, lm, lq);
    zpad(bufA, 136, tid);
    __syncthreads();

    // ---- glob[b][j] = (sum_n mask*h1)/msum -> grc
    for (int task = tid; task < 800; task += TB) {
        int b = task / 100, j = task - b * 100;
        float ms = msum[b];
        float inv = (ms > 0.f) ? 1.f / ms : 0.f;
        float a = 0.f;
        #pragma unroll
        for (int n = 0; n < 20; ++n)
            a = fmaf(maskv[b * 20 + n], b2f(bufA[(b * 20 + n) * 136 + j]), a);
        grc[task] = a * inv;
    }
    __syncthreads();

    // ---- gcon = atb0 + glob @ atw0[100:200] (register-staged overwrite)
    {
        float g0 = 0.f;
        if (tid < 800) {
            int b = tid / 100, j = tid - b * 100;
            float a = biasv[B_ATB0 + j];
            #pragma unroll 10
            for (int k = 0; k < 100; ++k)
                a = fmaf(grc[b * 100 + k], atw0[(100 + k) * 100 + j], a);
            g0 = a;
        }
        __syncthreads();
        if (tid < 800) grc[tid] = g0;
        stageW(m2w0, 100, 100, 128, 0, 112, 100, wbuf, 136, tid);
    }
    __syncthreads();

    // ---- m2L0 (100->100, relu): h1(bufA) -> bufT (t2)
    gemm<4, 2, true>(wbuf, 136, bufA, 136, bufT, 168, biasv + B_M2B0, 0,
                     7, 0, 100, wave, lm, lq);
    zpad(bufT, 168, tid);
    __syncthreads();
    stageW(m2w1, 50, 100, 128, 0, 64, 50, wbuf, 136, tid);
    __syncthreads();
    // ---- m2L1 (100->50, no relu): bufT -> bufH2 (h2)
    gemm<4, 5, false>(wbuf, 136, bufT, 168, bufH2, 72, biasv + B_M2B1, 0,
                      4, 0, 50, wave, lm, lq);
    __syncthreads();
    stageW(atw0, 100, 100, 128, 0, 112, 100, wbuf, 136, tid);
    __syncthreads();

    // ---- atL0 (100->100, relu, init=gcon): h1(bufA) -> bufT (ta)
    gemm<4, 2, true>(wbuf, 136, bufA, 136, bufT, 168, grc, 100,
                     7, 0, 100, wave, lm, lq);
    zpad(bufT, 168, tid);
    __syncthreads();
    stageW(atw1, 100, 100, 128, 0, 112, 100, wbuf, 136, tid);
    __syncthreads();
    // ---- atL1 (100->100, relu): bufT -> bufA (ta2)
    gemm<4, 2, true>(wbuf, 136, bufT, 168, bufA, 136, biasv + B_ATB1, 0,
                     7, 0, 100, wave, lm, lq);
    __syncthreads();

    // ---- scores + masked exp (matches reference semantics)
    if (tid < MTOK) {
        float s = atb2[0];
        const short* tp = bufA + tid * 136;
        #pragma unroll
        for (int k8 = 0; k8 < 13; ++k8) {
            sx8 v = *(const sx8*)(tp + k8 * 8);
            #pragma unroll
            for (int i = 0; i < 8; ++i) {
                int k = k8 * 8 + i;
                if (k < 100) s = fmaf(b2f(v[i]), atw2[k], s);
            }
        }
        s *= maskv[tid];
        scv[tid] = (s != 0.f) ? __expf(s) : 0.f;
    }
    __syncthreads();
    if (tid < 8) {
        float s = 0.f;
        #pragma unroll
        for (int n = 0; n < 20; ++n) s += scv[tid * 20 + n];
        ssum[tid] = s;
    }
    __syncthreads();
    if (tid < MTOK) {
        float ss = ssum[tid / 20];
        scv[tid] = (ss > 0.f) ? scv[tid] / ss : 0.f;
    }
    __syncthreads();

    // ---- wsum[b][j] = sum_n w*h2 -> wrc[0,400)
    if (tid < 400) {
        int b = tid / 50, j = tid - b * 50;
        float a = 0.f;
        #pragma unroll
        for (int n = 0; n < 20; ++n)
            a = fmaf(scv[b * 20 + n], b2f(bufH2[(b * 20 + n) * 72 + j]), a);
        wrc[b * 50 + j] = a;
    }
    __syncthreads();

    // ---- hcon = hpb0 + wsum @ hpw0[50:100] (register-staged overwrite)
    {
        float g0 = 0.f;
        if (tid < 800) {
            int b = tid / 100, j = tid - b * 100;
            float a = biasv[B_HPB0 + j];
            #pragma unroll 10
            for (int k = 0; k < 50; ++k)
                a = fmaf(wrc[b * 50 + k], hpw0[(50 + k) * 100 + j], a);
            g0 = a;
        }
        __syncthreads();
        if (tid < 800) wrc[tid] = g0;
        stageW(hpw0, 100, 50, 64, 0, 112, 100, wbuf, 72, tid);
    }
    __syncthreads();

    // ---- hpL0 (50->100, relu, init=hcon): h2(bufH2) -> bufT (th)
    gemm<2, 2, true>(wbuf, 72, bufH2, 72, bufT, 168, wrc, 100,
                     7, 0, 100, wave, lm, lq);
    zpad(bufT, 168, tid);
    __syncthreads();
    stageW(hpw1, 100, 100, 128, 0, 112, 100, wbuf, 136, tid);
    __syncthreads();
    // ---- hpL1 (100->100, relu): bufT -> bufA (th2)
    gemm<4, 2, true>(wbuf, 136, bufT, 168, bufA, 136, biasv + B_HPB1, 0,
                     7, 0, 100, wave, lm, lq);
    zpad(bufA, 136, tid);
    __syncthreads();
    stageW(hpw2, 7, 100, 128, 0, 16, 7, wbuf, 136, tid);
    __syncthreads();

    // ---- hpL2 (100->7) -> global out
    for (int mt = wave; mt < 10; mt += NW) {
        int tok = mt * 16 + lm;
        fx4 acc = *(const fx4*)(biasv + B_HPB2 + lq * 4);
        fx4 acc2 = {0.f, 0.f, 0.f, 0.f};
        const short* ap = wbuf + lm * 136 + lq * 8;
        const short* bp = bufA + tok * 136 + lq * 8;
        #pragma unroll
        for (int kt = 0; kt < 4; ++kt) {
            sx8 a = *(const sx8*)(ap + kt * 32);
            sx8 b = *(const sx8*)(bp + kt * 32);
            if (kt & 1)
                acc2 = __builtin_amdgcn_mfma_f32_16x16x32_bf16(a, b, acc2, 0, 0, 0);
            else
                acc = __builtin_amdgcn_mfma_f32_16x16x32_bf16(a, b, acc, 0, 0, 0);
        }
        acc[0] += acc2[0]; acc[1] += acc2[1]; acc[2] += acc2[2]; acc[3] += acc2[3];
        #pragma unroll
        for (int r = 0; r < 4; ++r) {
            int n = lq * 4 + r;
            if (n < 7) out[(gt0 + tok) * 7 + n] = acc[r];
        }
    }
}

extern "C" void kernel_launch(void* const* d_in, const int* in_sizes, int n_in,
                              void* d_out, int out_size, void* d_ws, size_t ws_size,
                              hipStream_t stream) {
    int si = 20, wb = 0;
    if (in_sizes[0] > 1000000) { si = 0; wb = 1; }
    const float* state = (const float*)d_in[si];
    const float* W[20];
    for (int i = 0; i < 20; ++i) W[i] = (const float*)d_in[wb + i];
    float* out = (float*)d_out;
    int Btot = in_sizes[si] / (20 * 14);
    int nblocks = Btot / 8;   // 8 b's (160 tokens) per block
    hipLaunchKernelGGL(sp_mfma_bf16, dim3(nblocks), dim3(TB), 0, stream,
        state,
        W[0], W[1], W[2], W[3],
        W[4], W[5], W[6], W[7],
        W[8], W[9], W[10], W[11], W[12], W[13],
        W[14], W[15], W[16], W[17], W[18], W[19],
        out);
}